// Round 8
// baseline (151.686 us; speedup 1.0000x reference)
//
#include <hip/hip_runtime.h>
#include <math.h>

// HumanPoseModule: (BT,10,6) + (BT,6,6) f32 -> (BT,24,3) f32 axis-angle.
//
// R14 (= R13 with compile fix): R7 compute + LDS-STAGED COALESCED NT OUTPUT.
// R13's only failure was __builtin_nontemporal_store rejecting HIP's
// float4 class type; fixed with a native clang ext_vector_type(4) alias.
//
// Evidence trail (R6-R12): dur tracks HBM bytes at ~2.4TB/s across every
// structural variant (126MB->49us; R11's amplified 175MB->76us; input
// staging / block size / occupancy 48-68% all no-ops) -> the kernel is
// HBM-byte-proportional, not latency- or issue-bound. Bytes = 74MB output
// (mandatory) + 49MB input re-fetch. The re-fetch exists because 74MB of
// write-allocate traffic evicts the 96MB inputs from the 256MB L3 between
// the bench's re-dispatches. Fix: stage each block's output (16 elem x
// 288B = 4608B) in LDS, then store as 288 contiguous float4 NT stores —
// full 64B sectors (R11's amplification came from scattered 12B NT
// stores), L3 untouched by writes, inputs stay resident.
// MARKERS: WRITE_SIZE stays ~73.7MB (no amplification); FETCH_SIZE <15MB
// (residency); dur ~ byte-proportional -> ~30-36us.
//
// Identity (R7): full[j] = root @ X_j, root orthonormal =>
// local[j] = X_parent^T @ X_j; joints 1,2,3: local = X_j; joint 0: root.
//
// Lane tables (byte-packed u64s; lane l = tid&15):
//   joints: {0,1,2,3,4,5,6,9,12,13,14,15,16,17,18,19}
//   srcj:   sel<<4|row  (sel 0 = glb row, 1 = ori row)
//   pl:     parent's lane within the 16-group (lanes 0-3 unused: direct)
// Ignored joints {7,8,10,11,20,21,22,23} -> zeros (staged into LDS).

typedef float f32x4 __attribute__((ext_vector_type(4)));   // NT-store-compatible

__device__ __forceinline__ void rot6d_v(float2 u0, float2 u1, float2 u2, float M[3][3]) {
    float a1x = u0.x, a1y = u0.y, a1z = u1.x;
    float a2x = u1.y, a2y = u2.x, a2z = u2.y;
    float r1 = __builtin_amdgcn_rsqf(a1x * a1x + a1y * a1y + a1z * a1z);
    float b1x = a1x * r1, b1y = a1y * r1, b1z = a1z * r1;
    float dt = b1x * a2x + b1y * a2y + b1z * a2z;
    float c2x = a2x - dt * b1x, c2y = a2y - dt * b1y, c2z = a2z - dt * b1z;
    float r2 = __builtin_amdgcn_rsqf(c2x * c2x + c2y * c2y + c2z * c2z);
    float b2x = c2x * r2, b2y = c2y * r2, b2z = c2z * r2;
    float b3x = b1y * b2z - b1z * b2y;
    float b3y = b1z * b2x - b1x * b2z;
    float b3z = b1x * b2y - b1y * b2x;
    M[0][0] = b1x; M[0][1] = b1y; M[0][2] = b1z;
    M[1][0] = b2x; M[1][1] = b2y; M[1][2] = b2z;
    M[2][0] = b3x; M[2][1] = b3y; M[2][2] = b3z;
}

// C = A^T @ B
__device__ __forceinline__ void matTmul(const float A[3][3], const float B[3][3], float C[3][3]) {
#pragma unroll
    for (int i = 0; i < 3; ++i)
#pragma unroll
        for (int j = 0; j < 3; ++j)
            C[i][j] = A[0][i] * B[0][j] + A[1][i] * B[1][j] + A[2][i] * B[2][j];
}

// atan2(y,x) for y >= 0, result in [0, pi]. Minimax atan poly on [0,1], err ~2e-8.
__device__ __forceinline__ float atan2_pos(float y, float x) {
    float ax = fabsf(x);
    float mx = fmaxf(y, ax);
    float mn = fminf(y, ax);
    float a = mn * __builtin_amdgcn_rcpf(mx);
    float s = a * a;
    float p = -0.0040540580f;
    p = fmaf(p, s, 0.0218612288f);
    p = fmaf(p, s, -0.0559098861f);
    p = fmaf(p, s, 0.0964200441f);
    p = fmaf(p, s, -0.1390853351f);
    p = fmaf(p, s, 0.1994653599f);
    p = fmaf(p, s, -0.3332985605f);
    p = fmaf(p, s, 0.9999993329f);
    float r = p * a;
    r = (y > ax) ? (1.5707963268f - r) : r;
    r = (x < 0.f) ? (3.1415926536f - r) : r;
    return r;
}

__device__ __forceinline__ void mat2aa(const float m[3][3], float* __restrict__ outp) {
    float m00 = m[0][0], m01 = m[0][1], m02 = m[0][2];
    float m10 = m[1][0], m11 = m[1][1], m12 = m[1][2];
    float m20 = m[2][0], m21 = m[2][1], m22 = m[2][2];
    float t0 = fmaxf(1.f + m00 + m11 + m22, 0.f);
    float t1 = fmaxf(1.f + m00 - m11 - m22, 0.f);
    float t2 = fmaxf(1.f - m00 + m11 - m22, 0.f);
    float t3 = fmaxf(1.f - m00 - m11 + m22, 0.f);
    // argmax over t == argmax over sqrt(t) (monotonic, same first-max ties)
    int idx = 0;
    float bt = t0;
    if (t1 > bt) { bt = t1; idx = 1; }
    if (t2 > bt) { bt = t2; idx = 2; }
    if (t3 > bt) { bt = t3; idx = 3; }
    float best = __builtin_amdgcn_sqrtf(bt);  // >= 1 always (sum of t == 4)
    float s1 = m21 - m12, s2 = m02 - m20, s3 = m10 - m01;
    float p1 = m10 + m01, p2 = m02 + m20, p3 = m12 + m21;
    float w = (idx == 0) ? bt : (idx == 1) ? s1 : (idx == 2) ? s2 : s3;
    float x = (idx == 0) ? s1 : (idx == 1) ? bt : (idx == 2) ? p1 : p2;
    float y = (idx == 0) ? s2 : (idx == 1) ? p1 : (idx == 2) ? bt : p3;
    float z = (idx == 0) ? s3 : (idx == 1) ? p2 : (idx == 2) ? p3 : bt;
    float inv = 0.5f * __builtin_amdgcn_rcpf(fmaxf(best, 0.1f));
    w *= inv; x *= inv; y *= inv; z *= inv;
    // unit quaternion: sin(half) == |v|, cos(half) == w
    float n = __builtin_amdgcn_sqrtf(x * x + y * y + z * z);
    float half = atan2_pos(n, w);
    float angle = 2.f * half;
    // angle < 1e-6 => ref's (0.5 - angle^2/48) rounds to 0.5 => inv_sh = 2
    float inv_sh = (angle < 1e-6f) ? 2.f : angle * __builtin_amdgcn_rcpf(n);
    outp[0] = x * inv_sh;
    outp[1] = y * inv_sh;
    outp[2] = z * inv_sh;
}

__global__ __launch_bounds__(256) void pose_kernel(const float* __restrict__ glb,
                                                   const float* __restrict__ ori,
                                                   float* __restrict__ out, int BT) {
    // output staging: 16 elements x 72 floats = 4608 B
    __shared__ float lds[16 * 72];

    int t = threadIdx.x;
    int base = blockIdx.x * 16;
    int eloc = t >> 4;
    int l = t & 15;
    int g = base + eloc;
    unsigned e = (unsigned)((g < BT) ? g : (BT - 1));   // clamp loads; stores bounded

    // byte-packed per-lane tables
    const unsigned long long OUT3_LO = 0x1B120F0C09060300ULL;  // joint*3, lanes 0-7
    const unsigned long long OUT3_HI = 0x393633302D2A2724ULL;  // lanes 8-15
    const unsigned long long SRCJ_LO = 0x0403121102010010ULL;
    const unsigned long long SRCJ_HI = 0x1514090813070605ULL;
    const unsigned long long PL_LO   = 0x0603020100000000ULL;  // parent lane, lanes 4-7
    const unsigned long long PL_HI   = 0x0D0C0A0908070707ULL;  // lanes 8-15
    const unsigned long long IGN3    = 0x45423F3C211E1815ULL;  // ignored joint*3, lanes 0-7

    int sh = (l & 7) * 8;
    unsigned out3 = (unsigned)(((l < 8 ? OUT3_LO : OUT3_HI) >> sh) & 0xFF);
    unsigned srcj = (unsigned)(((l < 8 ? SRCJ_LO : SRCJ_HI) >> sh) & 0xFF);
    int pl = (int)(((l < 8 ? PL_LO : PL_HI) >> sh) & 0xFF);

    // 32-bit offsets (e < 2^24): sgpr-base + voffset loads
    unsigned row6 = (srcj & 15) * 6;
    const float* src = (srcj & 0x10) ? (ori + __umul24(e, 36u) + row6)
                                     : (glb + __umul24(e, 60u) + row6);
    const float2* s2 = (const float2*)src;   // rows are 24B -> 8B aligned
    float2 u0 = s2[0], u1 = s2[1], u2 = s2[2];

    float X[3][3];
    rot6d_v(u0, u1, u2, X);

    // parent's X from the parent's lane (wave-synchronous, 16-lane groups)
    float Xp[3][3];
    {
        const float* xf = &X[0][0];
        float* pf = &Xp[0][0];
#pragma unroll
        for (int k = 0; k < 9; ++k) pf[k] = __shfl(xf[k], pl, 16);
    }

    // local = Xp^T @ X; lanes 0-3: local = X (parent is root / joint 0 is root)
    float L[3][3];
    matTmul(Xp, X, L);
#pragma unroll
    for (int i = 0; i < 3; ++i)
#pragma unroll
        for (int j = 0; j < 3; ++j)
            L[i][j] = (l < 4) ? X[i][j] : L[i][j];

    // stage this element's outputs in LDS
    float* op = lds + eloc * 72;
    mat2aa(L, op + out3);
    if (l < 8) {
        unsigned z = (unsigned)((IGN3 >> sh) & 0xFF);
        float* zp = op + z;
        zp[0] = 0.f; zp[1] = 0.f; zp[2] = 0.f;
    }
    __syncthreads();

    // coalesced non-temporal float4 stores: full 64B sectors per wave,
    // bypassing L3 so the 96MB of inputs stay L3-resident across dispatches.
    int nelem = BT - base;
    if (nelem > 16) nelem = 16;
    int nf4 = nelem * 18;                       // 288B/elem = 18 float4
    const f32x4* l4 = (const f32x4*)lds;
    f32x4* g4 = (f32x4*)(out + (size_t)base * 72);     // 288B-aligned
    for (int i = t; i < nf4; i += 256)
        __builtin_nontemporal_store(l4[i], g4 + i);
}

extern "C" void kernel_launch(void* const* d_in, const int* in_sizes, int n_in,
                              void* d_out, int out_size, void* d_ws, size_t ws_size,
                              hipStream_t stream) {
    const float* glb = (const float*)d_in[0];   // (BT,10,6) f32
    const float* ori = (const float*)d_in[1];   // (BT,6,6)  f32
    float* out = (float*)d_out;                 // (BT,24,3) f32
    int BT = in_sizes[0] / 60;
    int grid = (BT + 15) / 16;                  // 16 elements per 256-thread block
    pose_kernel<<<grid, 256, 0, stream>>>(glb, ori, out, BT);
}

// Round 9
// 151.483 us; speedup vs baseline: 1.0013x; 1.0013x over previous
//
#include <hip/hip_runtime.h>
#include <math.h>

// HumanPoseModule: (BT,10,6) + (BT,6,6) f32 -> (BT,24,3) f32 axis-angle.
//
// R15: FULLY-COALESCED MEMORY AT BOTH ENDS (completes the 2x2 matrix).
//   reads\writes   scattered     coalesced
//   scattered      R7: 47.5      R14: 49.2
//   coalesced      R10: 49       R15: THIS
// Every variant so far delivers ~2.5TB/s and ~49us regardless of which
// side is perfect -> either any single scattered path saturates the same
// memory queue (then R15 drops to ~33-38us), or ~49us is a structural
// floor invisible to these counters (then R15 == 49 and the session
// declares the roofline with the full matrix as evidence).
// Block = 16 elements: stage 6KB inputs via 384 coalesced float4 loads ->
// R7 root-free compute from LDS -> stage 4.5KB outputs in LDS -> 288
// coalesced NT float4 stores (full 64B sectors; R11 showed scattered NT
// stores amplify writes 65%).
//
// Identity (R7): full[j] = root @ X_j, root orthonormal =>
// local[j] = X_parent^T @ X_j; joints 1,2,3: local = X_j; joint 0: root.
//
// Lane tables (byte-packed u64s; lane l = tid&15):
//   joints: {0,1,2,3,4,5,6,9,12,13,14,15,16,17,18,19}
//   srcj:   sel<<4|row  (sel 0 = glb row, 1 = ori row)
//   pl:     parent's lane within the 16-group (lanes 0-3 unused: direct)
// Ignored joints {7,8,10,11,20,21,22,23} -> zeros (staged into LDS).

typedef float f32x4 __attribute__((ext_vector_type(4)));   // NT-store-compatible

__device__ __forceinline__ void rot6d_v(float2 u0, float2 u1, float2 u2, float M[3][3]) {
    float a1x = u0.x, a1y = u0.y, a1z = u1.x;
    float a2x = u1.y, a2y = u2.x, a2z = u2.y;
    float r1 = __builtin_amdgcn_rsqf(a1x * a1x + a1y * a1y + a1z * a1z);
    float b1x = a1x * r1, b1y = a1y * r1, b1z = a1z * r1;
    float dt = b1x * a2x + b1y * a2y + b1z * a2z;
    float c2x = a2x - dt * b1x, c2y = a2y - dt * b1y, c2z = a2z - dt * b1z;
    float r2 = __builtin_amdgcn_rsqf(c2x * c2x + c2y * c2y + c2z * c2z);
    float b2x = c2x * r2, b2y = c2y * r2, b2z = c2z * r2;
    float b3x = b1y * b2z - b1z * b2y;
    float b3y = b1z * b2x - b1x * b2z;
    float b3z = b1x * b2y - b1y * b2x;
    M[0][0] = b1x; M[0][1] = b1y; M[0][2] = b1z;
    M[1][0] = b2x; M[1][1] = b2y; M[1][2] = b2z;
    M[2][0] = b3x; M[2][1] = b3y; M[2][2] = b3z;
}

// C = A^T @ B
__device__ __forceinline__ void matTmul(const float A[3][3], const float B[3][3], float C[3][3]) {
#pragma unroll
    for (int i = 0; i < 3; ++i)
#pragma unroll
        for (int j = 0; j < 3; ++j)
            C[i][j] = A[0][i] * B[0][j] + A[1][i] * B[1][j] + A[2][i] * B[2][j];
}

// atan2(y,x) for y >= 0, result in [0, pi]. Minimax atan poly on [0,1], err ~2e-8.
__device__ __forceinline__ float atan2_pos(float y, float x) {
    float ax = fabsf(x);
    float mx = fmaxf(y, ax);
    float mn = fminf(y, ax);
    float a = mn * __builtin_amdgcn_rcpf(mx);
    float s = a * a;
    float p = -0.0040540580f;
    p = fmaf(p, s, 0.0218612288f);
    p = fmaf(p, s, -0.0559098861f);
    p = fmaf(p, s, 0.0964200441f);
    p = fmaf(p, s, -0.1390853351f);
    p = fmaf(p, s, 0.1994653599f);
    p = fmaf(p, s, -0.3332985605f);
    p = fmaf(p, s, 0.9999993329f);
    float r = p * a;
    r = (y > ax) ? (1.5707963268f - r) : r;
    r = (x < 0.f) ? (3.1415926536f - r) : r;
    return r;
}

__device__ __forceinline__ void mat2aa(const float m[3][3], float* __restrict__ outp) {
    float m00 = m[0][0], m01 = m[0][1], m02 = m[0][2];
    float m10 = m[1][0], m11 = m[1][1], m12 = m[1][2];
    float m20 = m[2][0], m21 = m[2][1], m22 = m[2][2];
    float t0 = fmaxf(1.f + m00 + m11 + m22, 0.f);
    float t1 = fmaxf(1.f + m00 - m11 - m22, 0.f);
    float t2 = fmaxf(1.f - m00 + m11 - m22, 0.f);
    float t3 = fmaxf(1.f - m00 - m11 + m22, 0.f);
    // argmax over t == argmax over sqrt(t) (monotonic, same first-max ties)
    int idx = 0;
    float bt = t0;
    if (t1 > bt) { bt = t1; idx = 1; }
    if (t2 > bt) { bt = t2; idx = 2; }
    if (t3 > bt) { bt = t3; idx = 3; }
    float best = __builtin_amdgcn_sqrtf(bt);  // >= 1 always (sum of t == 4)
    float s1 = m21 - m12, s2 = m02 - m20, s3 = m10 - m01;
    float p1 = m10 + m01, p2 = m02 + m20, p3 = m12 + m21;
    float w = (idx == 0) ? bt : (idx == 1) ? s1 : (idx == 2) ? s2 : s3;
    float x = (idx == 0) ? s1 : (idx == 1) ? bt : (idx == 2) ? p1 : p2;
    float y = (idx == 0) ? s2 : (idx == 1) ? p1 : (idx == 2) ? bt : p3;
    float z = (idx == 0) ? s3 : (idx == 1) ? p2 : (idx == 2) ? p3 : bt;
    float inv = 0.5f * __builtin_amdgcn_rcpf(fmaxf(best, 0.1f));
    w *= inv; x *= inv; y *= inv; z *= inv;
    // unit quaternion: sin(half) == |v|, cos(half) == w
    float n = __builtin_amdgcn_sqrtf(x * x + y * y + z * z);
    float half = atan2_pos(n, w);
    float angle = 2.f * half;
    // angle < 1e-6 => ref's (0.5 - angle^2/48) rounds to 0.5 => inv_sh = 2
    float inv_sh = (angle < 1e-6f) ? 2.f : angle * __builtin_amdgcn_rcpf(n);
    outp[0] = x * inv_sh;
    outp[1] = y * inv_sh;
    outp[2] = z * inv_sh;
}

__global__ __launch_bounds__(256) void pose_kernel(const float* __restrict__ glb,
                                                   const float* __restrict__ ori,
                                                   float* __restrict__ out, int BT) {
    // input staging: [glb 16x60 | ori 16x36] = 1536 f; output staging: 16x72 = 1152 f
    __shared__ float lin[16 * 60 + 16 * 36];
    __shared__ float lout[16 * 72];

    int t = threadIdx.x;
    int base = blockIdx.x * 16;
    int nelem = BT - base;
    if (nelem > 16) nelem = 16;

    // ---- stage inputs: 240 glb float4 + 144 ori float4, fully coalesced ----
    {
        float4* l4 = (float4*)lin;              // glb at f4[0..240), ori at f4[240..384)
        const float4* g4 = (const float4*)glb + (size_t)base * 15;  // 60 f = 15 f4
        const float4* o4 = (const float4*)ori + (size_t)base * 9;   // 36 f = 9 f4
        int ng = nelem * 15, no = nelem * 9;
#pragma unroll
        for (int i = t; i < 384; i += 256) {
            if (i < 240) {
                if (i < ng) l4[i] = g4[i];
            } else {
                int j = i - 240;
                if (j < no) l4[240 + j] = o4[j];
            }
        }
    }
    __syncthreads();

    int eloc = t >> 4;
    int l = t & 15;

    // byte-packed per-lane tables
    const unsigned long long OUT3_LO = 0x1B120F0C09060300ULL;  // joint*3, lanes 0-7
    const unsigned long long OUT3_HI = 0x393633302D2A2724ULL;  // lanes 8-15
    const unsigned long long SRCJ_LO = 0x0403121102010010ULL;
    const unsigned long long SRCJ_HI = 0x1514090813070605ULL;
    const unsigned long long PL_LO   = 0x0603020100000000ULL;  // parent lane, lanes 4-7
    const unsigned long long PL_HI   = 0x0D0C0A0908070707ULL;  // lanes 8-15
    const unsigned long long IGN3    = 0x45423F3C211E1815ULL;  // ignored joint*3, lanes 0-7

    int sh = (l & 7) * 8;
    unsigned out3 = (unsigned)(((l < 8 ? OUT3_LO : OUT3_HI) >> sh) & 0xFF);
    unsigned srcj = (unsigned)(((l < 8 ? SRCJ_LO : SRCJ_HI) >> sh) & 0xFF);
    int pl = (int)(((l < 8 ? PL_LO : PL_HI) >> sh) & 0xFF);

    // own X = rot6d(src row) read from LDS (3x ds_read_b64)
    unsigned row6 = (srcj & 15) * 6;
    const float* src = (srcj & 0x10) ? (lin + 960 + eloc * 36 + row6)
                                     : (lin + eloc * 60 + row6);
    const float2* s2 = (const float2*)src;      // 8B-aligned (24B-multiple offsets)
    float2 u0 = s2[0], u1 = s2[1], u2 = s2[2];

    float X[3][3];
    rot6d_v(u0, u1, u2, X);

    // parent's X from the parent's lane (wave-synchronous, 16-lane groups)
    float Xp[3][3];
    {
        const float* xf = &X[0][0];
        float* pf = &Xp[0][0];
#pragma unroll
        for (int k = 0; k < 9; ++k) pf[k] = __shfl(xf[k], pl, 16);
    }

    // local = Xp^T @ X; lanes 0-3: local = X (parent is root / joint 0 is root)
    float L[3][3];
    matTmul(Xp, X, L);
#pragma unroll
    for (int i = 0; i < 3; ++i)
#pragma unroll
        for (int j = 0; j < 3; ++j)
            L[i][j] = (l < 4) ? X[i][j] : L[i][j];

    // stage this element's outputs in LDS
    float* op = lout + eloc * 72;
    mat2aa(L, op + out3);
    if (l < 8) {
        unsigned z = (unsigned)((IGN3 >> sh) & 0xFF);
        float* zp = op + z;
        zp[0] = 0.f; zp[1] = 0.f; zp[2] = 0.f;
    }
    __syncthreads();

    // ---- coalesced NT float4 stores: full 64B sectors, bypass L3 ----
    int nf4 = nelem * 18;                       // 288B/elem = 18 float4
    const f32x4* l4 = (const f32x4*)lout;
    f32x4* g4 = (f32x4*)(out + (size_t)base * 72);     // 288B-aligned
    for (int i = t; i < nf4; i += 256)
        __builtin_nontemporal_store(l4[i], g4 + i);
}

extern "C" void kernel_launch(void* const* d_in, const int* in_sizes, int n_in,
                              void* d_out, int out_size, void* d_ws, size_t ws_size,
                              hipStream_t stream) {
    const float* glb = (const float*)d_in[0];   // (BT,10,6) f32
    const float* ori = (const float*)d_in[1];   // (BT,6,6)  f32
    float* out = (float*)d_out;                 // (BT,24,3) f32
    int BT = in_sizes[0] / 60;
    int grid = (BT + 15) / 16;                  // 16 elements per 256-thread block
    pose_kernel<<<grid, 256, 0, stream>>>(glb, ori, out, BT);
}

// Round 11
// 149.610 us; speedup vs baseline: 1.0139x; 1.0125x over previous
//
#include <hip/hip_runtime.h>
#include <math.h>

// HumanPoseModule: (BT,10,6) + (BT,6,6) f32 -> (BT,24,3) f32 axis-angle.
//
// R16 (resubmit — R10 bench was an infra failure, kernel never ran):
// QUATERNION-SPACE COMPOSITION (replaces matrix composition).
// Evidence (R6-R15): full 2x2 {scattered,coalesced}x{reads,writes} memory
// matrix all land at 48-49us (FETCH pinned 49.2MB, WRITE 73.7MB, VALU
// 44-46%, no pipe saturated); occupancy 48-68% no effect; ILP2 compiler-
// serialized 3x; persistent grid regressed. Remaining measured components:
// VALU issue ~21us (scales with op count) + ~9us shfl-lgkm exposure
// (appeared R6->R7 with the 9-float shfl chain). R16 attacks both:
//   matrix path:  rot6d(40) -> shfl x9 -> matTmul(36) -> mat2aa(60)
//   quat path:    rot6d(40) -> mat2quat(45) -> shfl x4 -> qmul(16)
//                 -> sign-fix(10) -> quat2aa(22)
// Identity: q(Xp^T Xc) = +-conj(q(Xp)) (x) q(Xc); ref's sign convention is
// q * sign(q[argmax |q_i|]) (candidate row idx has +q_abs^2 at idx), which
// the sign-fix replicates exactly (same first-max tie order w,x,y,z).
// Lanes 0-3: ql = qc (extraction already argmax-sign-normalized; sign-fix
// idempotent). Same O(1e-7) perturbation class as R7's root-cancellation
// (absmax stayed 0.03125 through all such changes).
//
// Lane tables (byte-packed u64s; lane l = tid&15):
//   joints: {0,1,2,3,4,5,6,9,12,13,14,15,16,17,18,19}
//   srcj:   sel<<4|row  (sel 0 = glb row, 1 = ori row)
//   pl:     parent's lane within the 16-group (lanes 0-3 unused: direct)
// Ignored joints {7,8,10,11,20,21,22,23} -> zeros, written by lanes 0-7.

__device__ __forceinline__ void rot6d_v(float2 u0, float2 u1, float2 u2, float M[3][3]) {
    float a1x = u0.x, a1y = u0.y, a1z = u1.x;
    float a2x = u1.y, a2y = u2.x, a2z = u2.y;
    float r1 = __builtin_amdgcn_rsqf(a1x * a1x + a1y * a1y + a1z * a1z);
    float b1x = a1x * r1, b1y = a1y * r1, b1z = a1z * r1;
    float dt = b1x * a2x + b1y * a2y + b1z * a2z;
    float c2x = a2x - dt * b1x, c2y = a2y - dt * b1y, c2z = a2z - dt * b1z;
    float r2 = __builtin_amdgcn_rsqf(c2x * c2x + c2y * c2y + c2z * c2z);
    float b2x = c2x * r2, b2y = c2y * r2, b2z = c2z * r2;
    float b3x = b1y * b2z - b1z * b2y;
    float b3y = b1z * b2x - b1x * b2z;
    float b3z = b1x * b2y - b1y * b2x;
    M[0][0] = b1x; M[0][1] = b1y; M[0][2] = b1z;
    M[1][0] = b2x; M[1][1] = b2y; M[1][2] = b2z;
    M[2][0] = b3x; M[2][1] = b3y; M[2][2] = b3z;
}

// ref-sequence matrix -> unit quaternion (argmax-candidate, first-max ties,
// sign convention: component[argmax] positive). This is the exact front
// half of the validated mat2aa.
__device__ __forceinline__ void mat2quat(const float m[3][3],
                                         float& qw, float& qx, float& qy, float& qz) {
    float m00 = m[0][0], m01 = m[0][1], m02 = m[0][2];
    float m10 = m[1][0], m11 = m[1][1], m12 = m[1][2];
    float m20 = m[2][0], m21 = m[2][1], m22 = m[2][2];
    float t0 = fmaxf(1.f + m00 + m11 + m22, 0.f);
    float t1 = fmaxf(1.f + m00 - m11 - m22, 0.f);
    float t2 = fmaxf(1.f - m00 + m11 - m22, 0.f);
    float t3 = fmaxf(1.f - m00 - m11 + m22, 0.f);
    int idx = 0;
    float bt = t0;
    if (t1 > bt) { bt = t1; idx = 1; }
    if (t2 > bt) { bt = t2; idx = 2; }
    if (t3 > bt) { bt = t3; idx = 3; }
    float best = __builtin_amdgcn_sqrtf(bt);  // >= 1 always (sum of t == 4)
    float s1 = m21 - m12, s2 = m02 - m20, s3 = m10 - m01;
    float p1 = m10 + m01, p2 = m02 + m20, p3 = m12 + m21;
    float w = (idx == 0) ? bt : (idx == 1) ? s1 : (idx == 2) ? s2 : s3;
    float x = (idx == 0) ? s1 : (idx == 1) ? bt : (idx == 2) ? p1 : p2;
    float y = (idx == 0) ? s2 : (idx == 1) ? p1 : (idx == 2) ? bt : p3;
    float z = (idx == 0) ? s3 : (idx == 1) ? p2 : (idx == 2) ? p3 : bt;
    float inv = 0.5f * __builtin_amdgcn_rcpf(fmaxf(best, 0.1f));
    qw = w * inv; qx = x * inv; qy = y * inv; qz = z * inv;
}

// atan2(y,x) for y >= 0, result in [0, pi]. Minimax atan poly on [0,1], err ~2e-8.
__device__ __forceinline__ float atan2_pos(float y, float x) {
    float ax = fabsf(x);
    float mx = fmaxf(y, ax);
    float mn = fminf(y, ax);
    float a = mn * __builtin_amdgcn_rcpf(mx);
    float s = a * a;
    float p = -0.0040540580f;
    p = fmaf(p, s, 0.0218612288f);
    p = fmaf(p, s, -0.0559098861f);
    p = fmaf(p, s, 0.0964200441f);
    p = fmaf(p, s, -0.1390853351f);
    p = fmaf(p, s, 0.1994653599f);
    p = fmaf(p, s, -0.3332985605f);
    p = fmaf(p, s, 0.9999993329f);
    float r = p * a;
    r = (y > ax) ? (1.5707963268f - r) : r;
    r = (x < 0.f) ? (3.1415926536f - r) : r;
    return r;
}

__global__ __launch_bounds__(256) void pose_kernel(const float* __restrict__ glb,
                                                   const float* __restrict__ ori,
                                                   float* __restrict__ out, int BT) {
    int tid = blockIdx.x * 256 + threadIdx.x;
    unsigned e = (unsigned)tid >> 4;
    if (e >= (unsigned)BT) return;
    int l = tid & 15;

    // byte-packed per-lane tables
    const unsigned long long OUT3_LO = 0x1B120F0C09060300ULL;  // joint*3, lanes 0-7
    const unsigned long long OUT3_HI = 0x393633302D2A2724ULL;  // lanes 8-15
    const unsigned long long SRCJ_LO = 0x0403121102010010ULL;
    const unsigned long long SRCJ_HI = 0x1514090813070605ULL;
    const unsigned long long PL_LO   = 0x0603020100000000ULL;  // parent lane, lanes 4-7
    const unsigned long long PL_HI   = 0x0D0C0A0908070707ULL;  // lanes 8-15
    const unsigned long long IGN3    = 0x45423F3C211E1815ULL;  // ignored joint*3, lanes 0-7

    int sh = (l & 7) * 8;
    unsigned out3 = (unsigned)(((l < 8 ? OUT3_LO : OUT3_HI) >> sh) & 0xFF);
    unsigned srcj = (unsigned)(((l < 8 ? SRCJ_LO : SRCJ_HI) >> sh) & 0xFF);
    int pl = (int)(((l < 8 ? PL_LO : PL_HI) >> sh) & 0xFF);

    // 32-bit offsets (e < 2^24): sgpr-base + voffset loads
    unsigned row6 = (srcj & 15) * 6;
    const float* src = (srcj & 0x10) ? (ori + __umul24(e, 36u) + row6)
                                     : (glb + __umul24(e, 60u) + row6);
    const float2* s2 = (const float2*)src;   // rows are 24B -> 8B aligned
    float2 u0 = s2[0], u1 = s2[1], u2 = s2[2];

    float X[3][3];
    rot6d_v(u0, u1, u2, X);

    // own quaternion (ref extraction, sign-normalized at argmax component)
    float qw, qx, qy, qz;
    mat2quat(X, qw, qx, qy, qz);

    // parent quaternion: 4 shfls (was 9 matrix shfls)
    float pw = __shfl(qw, pl, 16);
    float px = __shfl(qx, pl, 16);
    float py = __shfl(qy, pl, 16);
    float pz = __shfl(qz, pl, 16);

    // local quat = conj(qp) (x) qc ; lanes 0-3: local = own (parent is root
    // -> X_local = X; joint 0 -> root itself)
    float rw = pw * qw + px * qx + py * qy + pz * qz;
    float rx = pw * qx - px * qw - py * qz + pz * qy;
    float ry = pw * qy + px * qz - py * qw - pz * qx;
    float rz = pw * qz - px * qy + py * qx - pz * qw;
    bool direct = (l < 4);
    rw = direct ? qw : rw;
    rx = direct ? qx : rx;
    ry = direct ? qy : ry;
    rz = direct ? qz : rz;

    // ref sign convention: flip so component[first-argmax |comp|] positive
    {
        float aw = fabsf(rw), ax = fabsf(rx), ay = fabsf(ry), az = fabsf(rz);
        float m = aw; float c = rw;
        if (ax > m) { m = ax; c = rx; }
        if (ay > m) { m = ay; c = ry; }
        if (az > m) { m = az; c = rz; }
        unsigned sgn = __float_as_uint(c) & 0x80000000u;
        rw = __uint_as_float(__float_as_uint(rw) ^ sgn);
        rx = __uint_as_float(__float_as_uint(rx) ^ sgn);
        ry = __uint_as_float(__float_as_uint(ry) ^ sgn);
        rz = __uint_as_float(__float_as_uint(rz) ^ sgn);
    }

    // quat -> axis-angle (validated tail): sin(half) == |v|, cos(half) == w
    float n = __builtin_amdgcn_sqrtf(rx * rx + ry * ry + rz * rz);
    float half = atan2_pos(n, rw);
    float angle = 2.f * half;
    // angle < 1e-6 => ref's (0.5 - angle^2/48) rounds to 0.5 => inv_sh = 2
    float inv_sh = (angle < 1e-6f) ? 2.f : angle * __builtin_amdgcn_rcpf(n);

    float* oute = out + __umul24(e, 72u);
    float* op = oute + out3;
    op[0] = rx * inv_sh;
    op[1] = ry * inv_sh;
    op[2] = rz * inv_sh;

    // ignored joints -> exact zeros (lanes 0-7, one each)
    if (l < 8) {
        unsigned z = (unsigned)((IGN3 >> sh) & 0xFF);
        float* zp = oute + z;
        zp[0] = 0.f; zp[1] = 0.f; zp[2] = 0.f;
    }
}

extern "C" void kernel_launch(void* const* d_in, const int* in_sizes, int n_in,
                              void* d_out, int out_size, void* d_ws, size_t ws_size,
                              hipStream_t stream) {
    const float* glb = (const float*)d_in[0];   // (BT,10,6) f32
    const float* ori = (const float*)d_in[1];   // (BT,6,6)  f32
    float* out = (float*)d_out;                 // (BT,24,3) f32
    int BT = in_sizes[0] / 60;
    long long threads = (long long)BT * 16;
    int block = 256;
    int grid = (int)((threads + block - 1) / block);
    pose_kernel<<<grid, block, 0, stream>>>(glb, ori, out, BT);
}